// Round 3
// baseline (223.106 us; speedup 1.0000x reference)
//
#include <hip/hip_runtime.h>

// SSIM loss, fp32, x/y: (32,3,512,512), scalar mean output.
// R5: per-wave latency attack (R4 showed occupancy is scheduler-limited at
// ~11 waves/CU regardless of grid size, so TLP can't cover stalls).
//   - Shuffle-free horizontal taps: per input per row, TWO overlapping
//     dwordx4 loads at col offsets 4L-1 and 4L+1 (AMD global loads need only
//     4B alignment). Removes 4 ds_bpermute + lgkmcnt waits + lane-0/63
//     divergent halo loads from every iteration's critical path.
//   - Prefetch distance 2: two named row buffers (bufE/bufO), fully unrolled
//     loop so buffer selection is static (no scratch). Row loads issued ~2
//     iterations (~700 own-issue cycles) before use -> covers ~900-cycle HBM
//     miss latency (FETCH=134MB vs 260MB logical => ~half of reads miss L3).
//   - Edge lanes (vidx 0 / 127): clamped load address + component-select
//     patch implementing reflect, ~16 cndmask per row.
//   - Keep: RPW=8 (3072 blocks), tri3 prefix-pair sums, launch_bounds(256,4)
//     (R3 proved (256,8) causes catastrophic scratch spill).

#define IMG_H 512
#define IMG_W 512
#define N_PLANES 96                    // 32 * 3
#define TILE_W 256
#define N_TILES 2
#define RPW 8                          // rows per wave
#define WAVES_PER_BLOCK 4
#define ROWS_PER_BLOCK (RPW * WAVES_PER_BLOCK)          // 32
#define BLOCKS_PER_TILE (IMG_H / ROWS_PER_BLOCK)        // 16
#define N_MAIN_BLOCKS (N_PLANES * N_TILES * BLOCKS_PER_TILE)  // 3072
#define TOTAL_ELEMS 25165824.0f        // 32*3*512*512

typedef float f4 __attribute__((ext_vector_type(4), aligned(4)));

__device__ __forceinline__ int reflect512(int i) {
    i = i < 0 ? -i : i;
    return i > (IMG_H - 1) ? (2 * (IMG_H - 1) - i) : i;
}

// Raw overlapping loads for one input row pair:
//   A covers cols [4L-1 .. 4L+2], B covers cols [4L+1 .. 4L+4]
// (edge lanes use clamped addresses; component patch happens in build_h).
struct RowRaw { f4 xA, xB, yA, yB; };

__device__ __forceinline__ RowRaw issue_row(const float* __restrict__ px,
                                            const float* __restrict__ py,
                                            int r, int offA, int offB) {
    const int rr = reflect512(r);
    const size_t rowb = (size_t)rr * IMG_W;
    RowRaw o;
    o.xA = *(const f4*)(px + rowb + offA);
    o.xB = *(const f4*)(px + rowb + offB);
    o.yA = *(const f4*)(py + rowb + offA);
    o.yB = *(const f4*)(py + rowb + offB);
    return o;
}

struct H {           // horizontal 3-tap sums for this lane's 4 output columns
    float x[4], y[4], xx[4], yy[4], xy[4];
};

// 3-tap sums of 4 consecutive windows over 6 elements, sharing pair sums.
__device__ __forceinline__ void tri3(const float e[6], float o[4]) {
    const float p12 = e[1] + e[2];
    const float p34 = e[3] + e[4];
    o[0] = e[0] + p12;
    o[1] = p12 + e[3];
    o[2] = e[2] + p34;
    o[3] = p34 + e[5];
}

__device__ __forceinline__ H build_h(const RowRaw& rw, bool Ledge, bool Redge) {
    // Normal lanes: e = {A.x,A.y,A.z,A.w,B.z,B.w} = cols 4L-1..4L+4.
    float x6[6] = { rw.xA.x, rw.xA.y, rw.xA.z, rw.xA.w, rw.xB.z, rw.xB.w };
    float y6[6] = { rw.yA.x, rw.yA.y, rw.yA.z, rw.yA.w, rw.yB.z, rw.yB.w };
    if (Ledge) {
        // A clamped to col 0: {c0,c1,c2,c3}; desired {reflect(-1)=c1,c0,c1,c2}.
        x6[0] = rw.xA.y; x6[1] = rw.xA.x; x6[2] = rw.xA.y; x6[3] = rw.xA.z;
        y6[0] = rw.yA.y; y6[1] = rw.yA.x; y6[2] = rw.yA.y; y6[3] = rw.yA.z;
        // B (col 1..4) already supplies e4=c3=B.z, e5=c4=B.w.
    }
    if (Redge) {
        // B clamped to col 508: {c508..c511}; desired e4=c511=B.w,
        // e5=reflect(512)=c510=B.z. A (cols 507..510) already correct.
        x6[4] = rw.xB.w; x6[5] = rw.xB.z;
        y6[4] = rw.yB.w; y6[5] = rw.yB.z;
    }

    float xx6[6], yy6[6], xy6[6];
    #pragma unroll
    for (int i = 0; i < 6; ++i) {
        xx6[i] = x6[i] * x6[i];
        yy6[i] = y6[i] * y6[i];
        xy6[i] = x6[i] * y6[i];
    }
    H h;
    tri3(x6,  h.x);
    tri3(y6,  h.y);
    tri3(xx6, h.xx);
    tri3(yy6, h.yy);
    tri3(xy6, h.xy);
    return h;
}

__global__ __launch_bounds__(256, 4)
void ssim_main_kernel(const float* __restrict__ x, const float* __restrict__ y,
                      float* __restrict__ partials) {
    const int blk   = blockIdx.x;
    const int plane = blk / (N_TILES * BLOCKS_PER_TILE);
    const int rem   = blk % (N_TILES * BLOCKS_PER_TILE);
    const int tile  = rem / BLOCKS_PER_TILE;
    const int rblk  = rem % BLOCKS_PER_TILE;
    const int wave  = threadIdx.x >> 6;
    const int lane  = threadIdx.x & 63;

    const int c0   = tile * TILE_W;
    const int vidx = (c0 >> 2) + lane;                 // global float4 idx 0..127
    const bool Ledge = (vidx == 0);
    const bool Redge = (vidx == 127);
    const int offA = Ledge ? 0   : (4 * vidx - 1);     // float offset, 4B-aligned
    const int offB = Redge ? 508 : (4 * vidx + 1);
    const int r0   = (rblk * WAVES_PER_BLOCK + wave) * RPW;

    const float* px = x + (size_t)plane * (IMG_H * IMG_W);
    const float* py = y + (size_t)plane * (IMG_H * IMG_W);

    const float C1v  = 0.0001f;   // 0.01^2
    const float C2v  = 0.0009f;   // 0.03^2
    const float inv9 = 1.0f / 9.0f;

    // Prologue: rows r0-1, r0 in flight, then r0+1, r0+2 behind the builds.
    RowRaw bufE = issue_row(px, py, r0 - 1, offA, offB);
    RowRaw bufO = issue_row(px, py, r0,     offA, offB);
    H h0 = build_h(bufE, Ledge, Redge);
    bufE = issue_row(px, py, r0 + 1, offA, offB);
    H h1 = build_h(bufO, Ledge, Redge);
    bufO = issue_row(px, py, r0 + 2, offA, offB);

    float acc = 0.0f;
    #pragma unroll
    for (int i = 0; i < RPW; ++i) {
        // Consume the buffer issued 2 iterations ago; immediately refill it
        // with the row needed 2 iterations from now (reflect keeps addresses
        // in-bounds; trailing prefetches are unused).
        H h2;
        if ((i & 1) == 0) {
            h2 = build_h(bufE, Ledge, Redge);
            bufE = issue_row(px, py, r0 + 3 + i, offA, offB);
        } else {
            h2 = build_h(bufO, Ledge, Redge);
            bufO = issue_row(px, py, r0 + 3 + i, offA, offB);
        }

        #pragma unroll
        for (int j = 0; j < 4; ++j) {
            const float sx  = h0.x[j]  + h1.x[j]  + h2.x[j];
            const float sy  = h0.y[j]  + h1.y[j]  + h2.y[j];
            const float sxx = h0.xx[j] + h1.xx[j] + h2.xx[j];
            const float syy = h0.yy[j] + h1.yy[j] + h2.yy[j];
            const float sxy = h0.xy[j] + h1.xy[j] + h2.xy[j];

            const float mux   = sx * inv9;
            const float muy   = sy * inv9;
            const float mux2  = mux * mux;
            const float muy2  = muy * muy;
            const float muxy  = mux * muy;
            const float sigx  = fmaf(sxx, inv9, -mux2);
            const float sigy  = fmaf(syy, inv9, -muy2);
            const float sigxy = fmaf(sxy, inv9, -muxy);

            const float nume = (2.0f * muxy + C1v) * (2.0f * sigxy + C2v);
            const float deno = (mux2 + muy2 + C1v) * (sigx + sigy + C2v);
            float v = fmaf(nume, -__builtin_amdgcn_rcpf(deno), 1.0f) * 0.5f;
            v = fminf(fmaxf(v, 0.0f), 1.0f);
            acc += v;
        }

        h0 = h1;
        h1 = h2;
    }

    #pragma unroll
    for (int off = 32; off > 0; off >>= 1)
        acc += __shfl_down(acc, off);

    __shared__ float wave_sums[WAVES_PER_BLOCK];
    if (lane == 0) wave_sums[wave] = acc;
    __syncthreads();
    if (threadIdx.x == 0)
        partials[blk] = wave_sums[0] + wave_sums[1] + wave_sums[2] + wave_sums[3];
}

__global__ void ssim_reduce_kernel(const float* __restrict__ partials,
                                   float* __restrict__ out) {
    float acc = 0.0f;
    for (int i = threadIdx.x; i < N_MAIN_BLOCKS; i += 256)
        acc += partials[i];
    #pragma unroll
    for (int off = 32; off > 0; off >>= 1)
        acc += __shfl_down(acc, off);
    __shared__ float wave_sums[4];
    const int wave = threadIdx.x >> 6;
    const int lane = threadIdx.x & 63;
    if (lane == 0) wave_sums[wave] = acc;
    __syncthreads();
    if (threadIdx.x == 0)
        out[0] = (wave_sums[0] + wave_sums[1] + wave_sums[2] + wave_sums[3])
                 * (1.0f / TOTAL_ELEMS);
}

extern "C" void kernel_launch(void* const* d_in, const int* in_sizes, int n_in,
                              void* d_out, int out_size, void* d_ws, size_t ws_size,
                              hipStream_t stream) {
    const float* x = (const float*)d_in[0];
    const float* y = (const float*)d_in[1];
    float* out      = (float*)d_out;
    float* partials = (float*)d_ws;   // N_MAIN_BLOCKS floats (12 KiB)

    ssim_main_kernel<<<N_MAIN_BLOCKS, 256, 0, stream>>>(x, y, partials);
    ssim_reduce_kernel<<<1, 256, 0, stream>>>(partials, out);
}

// Round 5
// 217.067 us; speedup vs baseline: 1.0278x; 1.0278x over previous
//
#include <hip/hip_runtime.h>

// SSIM loss, fp32, x/y: (32,3,512,512), scalar mean output.
// R7: crash-proofed inline-asm load pipeline (R6 aborted on-GPU).
//   R6 defects fixed:
//   - one global_load per asm volatile, "=&v" early-clobber outputs
//     (R6 packed 2 loads/block with "=v": output regs could alias the shared
//     vaddr/saddr operand -> undefined behavior).
//   - plain 64-bit VGPR address ("v"(pointer) -> v[n:n+1], off): address
//     arithmetic is ordinary C++ the compiler checks; no hand-packed saddr.
//   Theory unchanged (R5 evidence): compiler sinks prefetches next to uses
//   (VGPR=56), so every wave holds only ~1 row of loads in flight ->
//   ~1.5 TB/s latency-bound (Little's law). Pin 3 rows (12 loads) in flight
//   per wave with counted s_waitcnt vmcnt(8), never 0 mid-loop.

#define IMG_H 512
#define IMG_W 512
#define N_PLANES 96                    // 32 * 3
#define TILE_W 256
#define N_TILES 2
#define RPW 8                          // rows per wave
#define WAVES_PER_BLOCK 4
#define ROWS_PER_BLOCK (RPW * WAVES_PER_BLOCK)          // 32
#define BLOCKS_PER_TILE (IMG_H / ROWS_PER_BLOCK)        // 16
#define N_MAIN_BLOCKS (N_PLANES * N_TILES * BLOCKS_PER_TILE)  // 3072
#define TOTAL_ELEMS 25165824.0f        // 32*3*512*512

typedef float f4 __attribute__((ext_vector_type(4)));

__device__ __forceinline__ int reflect512(int i) {
    i = i < 0 ? -i : i;
    return i > (IMG_H - 1) ? (2 * (IMG_H - 1) - i) : i;
}

// Overlapping 16B loads: A covers cols [4L-1..4L+2], B covers [4L+1..4L+4].
struct RowRaw { f4 xA, xB, yA, yB; };

struct H {           // horizontal 3-tap sums for this lane's 4 output columns
    float x[4], y[4], xx[4], yy[4], xy[4];
};

// 3-tap sums of 4 consecutive windows over 6 elements, sharing pair sums.
__device__ __forceinline__ void tri3(const float e[6], float o[4]) {
    const float p12 = e[1] + e[2];
    const float p34 = e[3] + e[4];
    o[0] = e[0] + p12;
    o[1] = p12 + e[3];
    o[2] = e[2] + p34;
    o[3] = p34 + e[5];
}

__device__ __forceinline__ H build_h(const RowRaw& rw, bool Ledge, bool Redge) {
    // Normal lanes: e = {A.x,A.y,A.z,A.w,B.z,B.w} = cols 4L-1..4L+4.
    float x6[6] = { rw.xA.x, rw.xA.y, rw.xA.z, rw.xA.w, rw.xB.z, rw.xB.w };
    float y6[6] = { rw.yA.x, rw.yA.y, rw.yA.z, rw.yA.w, rw.yB.z, rw.yB.w };
    if (Ledge) {
        // A clamped to col 0: {c0,c1,c2,c3}; desired {reflect(-1)=c1,c0,c1,c2}.
        x6[0] = rw.xA.y; x6[1] = rw.xA.x; x6[2] = rw.xA.y; x6[3] = rw.xA.z;
        y6[0] = rw.yA.y; y6[1] = rw.yA.x; y6[2] = rw.yA.y; y6[3] = rw.yA.z;
    }
    if (Redge) {
        // B clamped to col 508: {c508..c511}; desired e4=c511=B.w,
        // e5=reflect(512)=c510=B.z.
        x6[4] = rw.xB.w; x6[5] = rw.xB.z;
        y6[4] = rw.yB.w; y6[5] = rw.yB.z;
    }

    float xx6[6], yy6[6], xy6[6];
    #pragma unroll
    for (int i = 0; i < 6; ++i) {
        xx6[i] = x6[i] * x6[i];
        yy6[i] = y6[i] * y6[i];
        xy6[i] = x6[i] * y6[i];
    }
    H h;
    tri3(x6,  h.x);
    tri3(y6,  h.y);
    tri3(xx6, h.xx);
    tri3(yy6, h.yy);
    tri3(xy6, h.xy);
    return h;
}

__device__ __forceinline__ void ssim_step(const H& h0, const H& h1, const H& h2,
                                          float& acc) {
    const float C1v  = 0.0001f;   // 0.01^2
    const float C2v  = 0.0009f;   // 0.03^2
    const float inv9 = 1.0f / 9.0f;
    #pragma unroll
    for (int j = 0; j < 4; ++j) {
        const float sx  = h0.x[j]  + h1.x[j]  + h2.x[j];
        const float sy  = h0.y[j]  + h1.y[j]  + h2.y[j];
        const float sxx = h0.xx[j] + h1.xx[j] + h2.xx[j];
        const float syy = h0.yy[j] + h1.yy[j] + h2.yy[j];
        const float sxy = h0.xy[j] + h1.xy[j] + h2.xy[j];

        const float mux   = sx * inv9;
        const float muy   = sy * inv9;
        const float mux2  = mux * mux;
        const float muy2  = muy * muy;
        const float muxy  = mux * muy;
        const float sigx  = fmaf(sxx, inv9, -mux2);
        const float sigy  = fmaf(syy, inv9, -muy2);
        const float sigxy = fmaf(sxy, inv9, -muxy);

        const float nume = (2.0f * muxy + C1v) * (2.0f * sigxy + C2v);
        const float deno = (mux2 + muy2 + C1v) * (sigx + sigy + C2v);
        float v = fmaf(nume, -__builtin_amdgcn_rcpf(deno), 1.0f) * 0.5f;
        v = fminf(fmaxf(v, 0.0f), 1.0f);
        acc += v;
    }
}

// Issue one row's 4 loads via un-sinkable volatile asm. One instruction per
// asm block; "=&v" early-clobber so outputs can never alias the address
// operand; address is a plain C++ pointer -> 64-bit VGPR pair ("v[n:n+1], off").
#define ISSUE_ROW(BUF, ROW) do {                                          \
    const size_t ro_ = (size_t)reflect512(ROW) * IMG_W;                   \
    const float* pxA_ = pxA0 + ro_;                                       \
    const float* pxB_ = pxB0 + ro_;                                       \
    const float* pyA_ = pyA0 + ro_;                                       \
    const float* pyB_ = pyB0 + ro_;                                       \
    asm volatile("global_load_dwordx4 %0, %1, off"                        \
                 : "=&v"((BUF).xA) : "v"(pxA_));                          \
    asm volatile("global_load_dwordx4 %0, %1, off"                        \
                 : "=&v"((BUF).xB) : "v"(pxB_));                          \
    asm volatile("global_load_dwordx4 %0, %1, off"                        \
                 : "=&v"((BUF).yA) : "v"(pyA_));                          \
    asm volatile("global_load_dwordx4 %0, %1, off"                        \
                 : "=&v"((BUF).yB) : "v"(pyB_));                          \
} while (0)

// Counted wait for BUF's 4 loads (oldest outstanding). "+v" ties make all
// consumers data-depend on the post-wait values; sched_barrier per rule 18.
#define WAIT_ROW(BUF, NSTR) do {                                          \
    asm volatile("s_waitcnt vmcnt(" NSTR ")"                              \
                 : "+v"((BUF).xA), "+v"((BUF).xB),                        \
                   "+v"((BUF).yA), "+v"((BUF).yB));                       \
    __builtin_amdgcn_sched_barrier(0);                                    \
} while (0)

#define STEP(BUF) do {                                                    \
    H h2 = build_h((BUF), Ledge, Redge);                                  \
    ssim_step(h0, h1, h2, acc);                                           \
    h0 = h1; h1 = h2;                                                     \
} while (0)

__global__ __launch_bounds__(256, 3)
void ssim_main_kernel(const float* __restrict__ x, const float* __restrict__ y,
                      float* __restrict__ partials) {
    const int blk   = blockIdx.x;
    const int plane = blk / (N_TILES * BLOCKS_PER_TILE);
    const int rem   = blk % (N_TILES * BLOCKS_PER_TILE);
    const int tile  = rem / BLOCKS_PER_TILE;
    const int rblk  = rem % BLOCKS_PER_TILE;
    const int wave  = threadIdx.x >> 6;
    const int lane  = threadIdx.x & 63;

    const int c0   = tile * TILE_W;
    const int vidx = (c0 >> 2) + lane;                 // global float4 idx 0..127
    const bool Ledge = (vidx == 0);
    const bool Redge = (vidx == 127);
    const int offA = Ledge ? 0   : (4 * vidx - 1);     // float offsets, 4B-aligned
    const int offB = Redge ? 508 : (4 * vidx + 1);
    const int r0   = (rblk * WAVES_PER_BLOCK + wave) * RPW;

    const float* px = x + (size_t)plane * (IMG_H * IMG_W);
    const float* py = y + (size_t)plane * (IMG_H * IMG_W);
    const float* pxA0 = px + offA;
    const float* pxB0 = px + offB;
    const float* pyA0 = py + offA;
    const float* pyB0 = py + offB;

    RowRaw B0, B1, B2;
    float acc = 0.0f;

    // Pipeline prologue: rows r0-1, r0, r0+1 in flight (12 loads).
    ISSUE_ROW(B0, r0 - 1);
    ISSUE_ROW(B1, r0);
    ISSUE_ROW(B2, r0 + 1);
    WAIT_ROW(B0, "8");
    H h0 = build_h(B0, Ledge, Redge);
    ISSUE_ROW(B0, r0 + 2);
    WAIT_ROW(B1, "8");
    H h1 = build_h(B1, Ledge, Redge);

    // Steady state: issue row k+2, wait row k (vmcnt(8) = 2 rows still in
    // flight), consume. Rows consumed: r0+1 .. r0+8. No trailing waste.
    ISSUE_ROW(B1, r0 + 3); WAIT_ROW(B2, "8"); STEP(B2);
    ISSUE_ROW(B2, r0 + 4); WAIT_ROW(B0, "8"); STEP(B0);
    ISSUE_ROW(B0, r0 + 5); WAIT_ROW(B1, "8"); STEP(B1);
    ISSUE_ROW(B1, r0 + 6); WAIT_ROW(B2, "8"); STEP(B2);
    ISSUE_ROW(B2, r0 + 7); WAIT_ROW(B0, "8"); STEP(B0);
    ISSUE_ROW(B0, r0 + 8); WAIT_ROW(B1, "8"); STEP(B1);
    /* drain */            WAIT_ROW(B2, "4"); STEP(B2);
    /* drain */            WAIT_ROW(B0, "0"); STEP(B0);

    #pragma unroll
    for (int off = 32; off > 0; off >>= 1)
        acc += __shfl_down(acc, off);

    __shared__ float wave_sums[WAVES_PER_BLOCK];
    if (lane == 0) wave_sums[wave] = acc;
    __syncthreads();
    if (threadIdx.x == 0)
        partials[blk] = wave_sums[0] + wave_sums[1] + wave_sums[2] + wave_sums[3];
}

__global__ void ssim_reduce_kernel(const float* __restrict__ partials,
                                   float* __restrict__ out) {
    float acc = 0.0f;
    for (int i = threadIdx.x; i < N_MAIN_BLOCKS; i += 256)
        acc += partials[i];
    #pragma unroll
    for (int off = 32; off > 0; off >>= 1)
        acc += __shfl_down(acc, off);
    __shared__ float wave_sums[4];
    const int wave = threadIdx.x >> 6;
    const int lane = threadIdx.x & 63;
    if (lane == 0) wave_sums[wave] = acc;
    __syncthreads();
    if (threadIdx.x == 0)
        out[0] = (wave_sums[0] + wave_sums[1] + wave_sums[2] + wave_sums[3])
                 * (1.0f / TOTAL_ELEMS);
}

extern "C" void kernel_launch(void* const* d_in, const int* in_sizes, int n_in,
                              void* d_out, int out_size, void* d_ws, size_t ws_size,
                              hipStream_t stream) {
    const float* x = (const float*)d_in[0];
    const float* y = (const float*)d_in[1];
    float* out      = (float*)d_out;
    float* partials = (float*)d_ws;   // N_MAIN_BLOCKS floats (12 KiB)

    ssim_main_kernel<<<N_MAIN_BLOCKS, 256, 0, stream>>>(x, y, partials);
    ssim_reduce_kernel<<<1, 256, 0, stream>>>(partials, out);
}